// Round 12
// baseline (334.210 us; speedup 1.0000x reference)
//
#include <hip/hip_runtime.h>
#include <math.h>

#define B_SZ  2
#define L_SEQ 8192
#define EMB   1024
#define NH    16
#define HDIM  64
#define WIN   128
#define MROWS (B_SZ*L_SEQ)

typedef __attribute__((ext_vector_type(8))) _Float16 f16x8;
typedef __attribute__((ext_vector_type(4))) _Float16 f16x4;
typedef __attribute__((ext_vector_type(4))) float f32x4;

__device__ __forceinline__ void gload16(const void* g, void* l) {
    __builtin_amdgcn_global_load_lds(
        (const __attribute__((address_space(1))) unsigned int*)g,
        (__attribute__((address_space(3))) unsigned int*)l, 16, 0, 0);
}

// ---------------- fused fp32 -> fp16 rounds (x + 4 weights) ----------------
__global__ __launch_bounds__(256)
void round_all(const float* __restrict__ x,
               const float* __restrict__ wq, const float* __restrict__ wk,
               const float* __restrict__ wv, const float* __restrict__ wo,
               _Float16* __restrict__ xf, _Float16* __restrict__ q16,
               _Float16* __restrict__ k16, _Float16* __restrict__ v16,
               _Float16* __restrict__ o16)
{
    const size_t NX = (size_t)MROWS * EMB, NW = (size_t)EMB * EMB;
    size_t gid = ((size_t)blockIdx.x * 256 + threadIdx.x) * 4;
    const float* src; _Float16* dst; size_t off;
    if (gid < NX)               { src = x;  dst = xf;  off = gid; }
    else if (gid < NX + NW)     { src = wq; dst = q16; off = gid - NX; }
    else if (gid < NX + 2*NW)   { src = wk; dst = k16; off = gid - NX - 2*NW + NW; }
    else if (gid < NX + 3*NW)   { src = wv; dst = v16; off = gid - NX - 2*NW; }
    else                        { src = wo; dst = o16; off = gid - NX - 3*NW; }
    float4 v = *(const float4*)(src + off);
    f16x4 o;
    o[0] = (_Float16)v.x; o[1] = (_Float16)v.y;
    o[2] = (_Float16)v.z; o[3] = (_Float16)v.w;
    *(f16x4*)(dst + off) = o;
}

// ============================================================================
// 256x256 GEMM, BK=64, 8 waves (2Mx4N), 128 KiB double-buffered LDS.
// R4 tail-read schedule + B0-HOLD (best measured). FROZEN.
// ============================================================================

#define STAGE_HT(ptr_, tb_, op_, h_, kt_)                                      \
    {                                                                          \
        char* d_ = smem + (op_) * 65536 + ((kt_) & 1) * 32768 + (h_) * 16384 + ldst; \
        const _Float16* s_ = (ptr_) + ((size_t)((tb_) + (h_) * 128 + srow6)) * 1024 + (kt_) * 64 + gch; \
        gload16(s_, d_);                                                       \
        gload16(s_ + 64 * 1024, d_ + 8192);                                    \
    }

#define DSREAD_A(qr_)                                                          \
    _Pragma("unroll")                                                          \
    for (int i_ = 0; i_ < 4; ++i_) {                                           \
        const int ro_ = (qr_) * 8192 + (i_ * 16 + frow) * 128;                 \
        af[i_][0] = *(const f16x8*)(Ab + ro_ + sb0);                           \
        af[i_][1] = *(const f16x8*)(Ab + ro_ + sb1);                           \
    }

#define DSREAD_B_TO(dst_, qc_)                                                 \
    _Pragma("unroll")                                                          \
    for (int j_ = 0; j_ < 2; ++j_) {                                           \
        const int ro_ = (brow + (qc_) * 32 + j_ * 16 + frow) * 128;            \
        dst_[j_][0] = *(const f16x8*)(Bb + ro_ + sb0);                         \
        dst_[j_][1] = *(const f16x8*)(Bb + ro_ + sb1);                         \
    }

#define MFMA16(qr_, qc_, barr_)                                                \
    __builtin_amdgcn_s_setprio(1);                                             \
    _Pragma("unroll")                                                          \
    for (int ks_ = 0; ks_ < 2; ++ks_)                                          \
        _Pragma("unroll")                                                      \
        for (int i_ = 0; i_ < 4; ++i_)                                         \
            _Pragma("unroll")                                                  \
            for (int j_ = 0; j_ < 2; ++j_)                                     \
                acc[(qr_) * 4 + i_][(qc_) * 2 + j_] =                          \
                    __builtin_amdgcn_mfma_f32_16x16x32_f16(                    \
                        af[i_][ks_], barr_[j_][ks_],                           \
                        acc[(qr_) * 4 + i_][(qc_) * 2 + j_], 0, 0, 0);         \
    __builtin_amdgcn_s_setprio(0);

#define BARM()                                                                 \
    asm volatile("" ::: "memory");                                             \
    __builtin_amdgcn_s_barrier();                                              \
    asm volatile("" ::: "memory");

#define GEMM8_CORE(Aptr, Bptr)                                                 \
    const int t = threadIdx.x;                                                 \
    const int wave = t >> 6, lane = t & 63;                                    \
    const int wr = wave >> 2, wc = wave & 3;                                   \
    const int frow = lane & 15, quad = lane >> 4;                              \
    const int srow6 = t >> 3;                                                  \
    const int gch = ((t & 7) ^ (srow6 & 7)) * 8;                               \
    const int ldst = t * 16;                                                   \
    const int sb0 = (quad ^ (frow & 7)) * 16, sb1 = sb0 ^ 64;                  \
    const int brow = (wc & 1) * 64;                                            \
    f32x4 acc[8][4] = {};                                                      \
    f16x8 af[4][2], bfA[2][2], bfB[2][2];                                      \
    STAGE_HT(Aptr, bm, 0, 0, 0) STAGE_HT(Aptr, bm, 0, 1, 0)                    \
    STAGE_HT(Bptr, bn, 1, 0, 0) STAGE_HT(Bptr, bn, 1, 1, 0)                    \
    for (int kt = 0; kt < 16; ++kt) {                                          \
        const char* Ab = smem + (kt & 1) * 32768 + wr * 16384;                 \
        const char* Bb = smem + 65536 + (kt & 1) * 32768 + (wc >> 1) * 16384;  \
        if (kt < 15) {                                                         \
            STAGE_HT(Aptr, bm, 0, 0, kt + 1)                                   \
            asm volatile("s_waitcnt vmcnt(2)" ::: "memory");                   \
        } else {                                                               \
            asm volatile("s_waitcnt vmcnt(0)" ::: "memory");                   \
        }                                                                      \
        BARM()                                                                 \
        DSREAD_A(0) DSREAD_B_TO(bfA, 0)  /* boundary reads (exposed) */        \
        MFMA16(0, 0, bfA)                                                      \
        DSREAD_B_TO(bfB, 1)              /* tail-read for next section */      \
        if (kt < 15) STAGE_HT(Aptr, bm, 0, 1, kt + 1)                          \
        BARM()                                                                 \
        MFMA16(0, 1, bfB)                                                      \
        DSREAD_A(1)                                                            \
        if (kt < 15) STAGE_HT(Bptr, bn, 1, 0, kt + 1)                          \
        BARM()                                                                 \
        MFMA16(1, 1, bfB)                                                      \
        if (kt < 15) STAGE_HT(Bptr, bn, 1, 1, kt + 1)                          \
        BARM()                                                                 \
        MFMA16(1, 0, bfA)                /* reuses held B0 — no re-read */     \
        BARM()                                                                 \
    }

// ---------------- fused QKV GEMM (split: one dispatch per wsel) ------------
__global__ __launch_bounds__(512, 2)
void gemm_qkv(const _Float16* __restrict__ X,
              const _Float16* __restrict__ Wq, const _Float16* __restrict__ Wk,
              const _Float16* __restrict__ Wv,
              const float* __restrict__ bq, const float* __restrict__ bk,
              const float* __restrict__ bv,
              _Float16* __restrict__ qf, _Float16* __restrict__ kf,
              _Float16* __restrict__ vtf, const int wsel)
{
    __shared__ __attribute__((aligned(16))) char smem[131072];

    const int id = blockIdx.x;
    const int row = (id / 32) * 8 + (id & 7);   // 4 col-blocks of a row -> 1 XCD
    const int bm = row * 256, bn = ((id >> 3) & 3) * 256;
    const _Float16* Bw = wsel == 0 ? Wq : wsel == 1 ? Wk : Wv;
    const float* bias = wsel == 0 ? bq : wsel == 1 ? bk : bv;
    const float scale = wsel == 0 ? 0.125f : 1.0f;

    GEMM8_CORE(X, Bw)

    // ---- epilogue: per-wave 8KB LDS slice (no cross-wave sync needed) ----
    char* Cw = smem + wave * 8192;              // 64 rows x 128B, XOR-swizzled
    const int bb = bm >> 13;
    const int l0 = (bm & (L_SEQ - 1)) + wr * 128;
    const int h = (bn >> 6) + wc;
    if (wsel < 2) {
        _Float16* dst = wsel == 0 ? qf : kf;
        const size_t hb = ((size_t)(bb * NH + h)) * L_SEQ * HDIM;
        #pragma unroll
        for (int ih = 0; ih < 2; ++ih) {
            asm volatile("" ::: "memory");
            #pragma unroll
            for (int i = 0; i < 4; ++i)
                #pragma unroll
                for (int j = 0; j < 4; ++j) {
                    const int lc = j * 16 + frow;
                    const float bvv = bias[bn + wc * 64 + lc];
                    #pragma unroll
                    for (int r = 0; r < 4; ++r) {
                        const int lr = i * 16 + quad * 4 + r;
                        const int bo = lr * 128 + ((lc * 2) ^ ((lr & 7) << 4));
                        *(_Float16*)(Cw + bo) = (_Float16)((acc[ih * 4 + i][j][r] + bvv) * scale);
                    }
                }
            asm volatile("" ::: "memory");
            #pragma unroll
            for (int p = 0; p < 8; ++p) {
                const int idx = p * 64 + lane;
                const int lr = idx >> 3, seg = idx & 7;
                const int bo = lr * 128 + ((seg * 16) ^ ((lr & 7) << 4));
                uint4 v = *(const uint4*)(Cw + bo);
                *(uint4*)&dst[hb + (size_t)(l0 + ih * 64 + lr) * HDIM + seg * 8] = v;
            }
        }
    } else {
        // V: stage transposed (col-major) so stores are contiguous along L
        const size_t hb = ((size_t)(bb * NH + h)) * HDIM * L_SEQ;
        #pragma unroll
        for (int ih = 0; ih < 2; ++ih) {
            asm volatile("" ::: "memory");
            #pragma unroll
            for (int i = 0; i < 4; ++i)
                #pragma unroll
                for (int j = 0; j < 4; ++j) {
                    const int lc = j * 16 + frow;
                    const float bvv = bias[bn + wc * 64 + lc];
                    #pragma unroll
                    for (int r = 0; r < 4; ++r) {
                        const int lr = i * 16 + quad * 4 + r;
                        const int bo = lc * 128 + ((lr * 2) ^ ((lc & 7) << 4));
                        *(_Float16*)(Cw + bo) = (_Float16)(acc[ih * 4 + i][j][r] + bvv);
                    }
                }
            asm volatile("" ::: "memory");
            #pragma unroll
            for (int p = 0; p < 8; ++p) {
                const int idx = p * 64 + lane;
                const int dc = idx >> 3, sl = idx & 7;
                const int bo = dc * 128 + ((sl * 16) ^ ((dc & 7) << 4));
                uint4 v = *(const uint4*)(Cw + bo);
                *(uint4*)&vtf[hb + (size_t)dc * L_SEQ + (l0 + ih * 64 + sl * 8)] = v;
            }
        }
    }
}

// ---------------- output GEMM ----------------
__global__ __launch_bounds__(512, 2)
void gemm_out(const _Float16* __restrict__ A, const _Float16* __restrict__ Bwm,
              const float* __restrict__ bias, float* __restrict__ C)
{
    constexpr int N = EMB;
    __shared__ __attribute__((aligned(16))) char smem[131072];

    const int id = blockIdx.x;
    const int row = (id / 32) * 8 + (id & 7);
    const int bm = row * 256, bn = ((id >> 3) & 3) * 256;

    GEMM8_CORE(A, Bwm)

    // ---- epilogue: direct f32 stores (64B contiguous per row-segment) ----
    #pragma unroll
    for (int i = 0; i < 8; ++i) {
        int m0 = bm + wr * 128 + i * 16 + quad * 4;
        #pragma unroll
        for (int j = 0; j < 4; ++j) {
            int n = bn + wc * 64 + j * 16 + frow;
            float bvv = bias[n];
            #pragma unroll
            for (int r = 0; r < 4; ++r)
                C[(size_t)(m0 + r) * N + n] = acc[i][j][r] + bvv;
        }
    }
}

// ---------------- banded flash attention, fp16 MFMA, 128-query tiles -------
// ALL-TILES-UPFRONT: stage all 6 K/V tiles (96 KiB LDS) with one vmcnt(0) +
// one barrier, then a completely barrier-free per-wave section loop (was 12
// lockstep barriers). XCD-contiguity swizzle xq=(xi&7)*8+(xi>>3): each XCD
// owns a contiguous 8-block q-span -> neighboring blocks' shared K/V tiles
// hit the same XCD's L2 instead of being re-fetched from HBM by 6 XCDs.
// Section math identical to R8/R10: swapped QK^T, in-register P^T,
// mfma_16x16x16 PV, no-max softmax, deferred row-sum, mask elision.
__global__ __launch_bounds__(512)
void attn_mfma(const _Float16* __restrict__ qf, const _Float16* __restrict__ kf,
               const _Float16* __restrict__ vtf, _Float16* __restrict__ cf)
{
    __shared__ _Float16 Kt[6][4096];    // 48 KB
    __shared__ _Float16 Vt[6][4096];    // 48 KB

    const int t = threadIdx.x;
    const int wave = t >> 6, lane = t & 63;
    const int col = lane & 15, quad = lane >> 4;
    const int bh = blockIdx.y;
    const int xi = blockIdx.x;
    const int xq = (xi & 7) * 8 + (xi >> 3);        // XCD-contiguous q-span
    const int q0 = xq * 128;
    const int oo = wave * 16;                       // wave's 16-row band

    // ---- stage ALL valid K/V tiles; Q frag loads overlap the latency ----
    const int srow = t >> 3, sc = t & 7;
    const int gq = sc ^ (srow & 7);
    #pragma unroll
    for (int kt = 0; kt < 6; kt++) {
        const int p0s = q0 - WIN + kt * 64;
        if (p0s < 0 || p0s >= L_SEQ) continue;      // block-uniform
        size_t kgi = ((size_t)bh * L_SEQ + p0s + srow) * HDIM + gq * 8;
        size_t vgi = ((size_t)bh * HDIM + srow) * L_SEQ + p0s + gq * 8;
        gload16(kf + kgi, (char*)&Kt[kt][0] + t * 16);
        gload16(vtf + vgi, (char*)&Vt[kt][0] + t * 16);
    }

    f16x8 qfr[2];
    {
        size_t qidx = ((size_t)bh * L_SEQ + q0 + oo + col) * HDIM + quad * 8;
        qfr[0] = *(const f16x8*)(qf + qidx);
        qfr[1] = *(const f16x8*)(qf + qidx + 32);
    }

    asm volatile("s_waitcnt vmcnt(0)" ::: "memory");
    __builtin_amdgcn_s_barrier();
    asm volatile("" ::: "memory");

    f32x4 o[4] = {};          // o[m][r] = O[q=col][d=m*16+quad*4+r]
    float lsum = 0.0f;

    // ---- barrier-free section loop ----
    #pragma unroll
    for (int kt = 0; kt < 6; kt++) {
        const int p0 = q0 - WIN + kt * 64;
        if (p0 < 0 || p0 >= L_SEQ) continue;        // block-uniform
        const int relp = kt * 64 - WIN - oo;
        if (relp < -191 || relp > 143) continue;    // wave-uniform

        const char* Kb = (const char*)&Kt[kt][0];
        const char* Vb = (const char*)&Vt[kt][0];

        // ---- S^T = K Q^T ----
        f32x4 sT[4] = {};
        #pragma unroll
        for (int ks = 0; ks < 2; ks++)
            #pragma unroll
            for (int n = 0; n < 4; n++) {
                int off = (n * 16 + col) * 128 + (((ks * 4 + quad) ^ (col & 7)) * 16);
                f16x8 kfr = *(const f16x8*)(Kb + off);
                sT[n] = __builtin_amdgcn_mfma_f32_16x16x32_f16(kfr, qfr[ks], sT[n], 0, 0, 0);
            }
        // ---- band mask: only edge-clipped sections ----
        if (relp < -113 || relp > 65) {
            const int qrow = q0 + oo + col;
            #pragma unroll
            for (int n = 0; n < 4; n++)
                #pragma unroll
                for (int r = 0; r < 4; r++) {
                    int dlt = (p0 + n * 16 + quad * 4 + r) - qrow;
                    if (dlt < -WIN || dlt > WIN) sT[n][r] = -3e38f;
                }
        }
        // ---- exp, per-lane sums, pack P^T in regs ----
        f16x4 pT[4];
        #pragma unroll
        for (int n = 0; n < 4; n++)
            #pragma unroll
            for (int r = 0; r < 4; r++) {
                float pv = __expf(sT[n][r]);
                lsum += pv;
                pT[n][r] = (_Float16)pv;
            }
        // ---- O^T += V^T P^T via mfma_16x16x16 ----
        #pragma unroll
        for (int m = 0; m < 4; m++) {
            #pragma unroll
            for (int n = 0; n < 4; n++) {
                int off = (m * 16 + col) * 128 +
                          (((2 * n + (quad >> 1)) ^ (col & 7)) * 16) + (quad & 1) * 8;
                f16x4 vfr = *(const f16x4*)(Vb + off);
                o[m] = __builtin_amdgcn_mfma_f32_16x16x16f16(vfr, pT[n], o[m], 0, 0, 0);
            }
        }
    }

    // ---- deferred row-sum reduction over the 4 quad-lanes ----
    lsum += __shfl_xor(lsum, 16, 64);
    lsum += __shfl_xor(lsum, 32, 64);
    const float inv = 1.0f / lsum;

    // ---- normalize, store ctx fp16 (B,L,E): 4x 8B vector stores/lane ----
    const int b = bh >> 4, h = bh & 15;
    const size_t base = ((size_t)b * L_SEQ + q0 + oo + col) * EMB + h * HDIM;
    #pragma unroll
    for (int m = 0; m < 4; m++) {
        f16x4 ov;
        #pragma unroll
        for (int r = 0; r < 4; r++) ov[r] = (_Float16)(o[m][r] * inv);
        *(f16x4*)&cf[base + m * 16 + quad * 4] = ov;
    }
}

extern "C" void kernel_launch(void* const* d_in, const int* in_sizes, int n_in,
                              void* d_out, int out_size, void* d_ws, size_t ws_size,
                              hipStream_t stream) {
    const float* x  = (const float*)d_in[0];
    const float* Wq = (const float*)d_in[1];
    const float* Wk = (const float*)d_in[2];
    const float* Wv = (const float*)d_in[3];
    const float* Wo = (const float*)d_in[4];
    const float* bq = (const float*)d_in[5];
    const float* bk = (const float*)d_in[6];
    const float* bv = (const float*)d_in[7];
    const float* bo = (const float*)d_in[8];
    float* out = (float*)d_out;

    const size_t per = (size_t)B_SZ * NH * L_SEQ * HDIM;   // 16.7M elements
    _Float16* w16 = (_Float16*)d_ws;
    _Float16* xf   = w16;
    _Float16* qf   = w16 + per;       // (B,H,L,64), pre-scaled 1/8
    _Float16* kf   = w16 + 2 * per;
    _Float16* vtf  = w16 + 3 * per;   // (B,H,64,L)
    _Float16* cf   = w16 + 4 * per;   // ctx (B,L,E)
    _Float16* wq16 = w16 + 5 * per;
    _Float16* wk16 = wq16 + 1048576;
    _Float16* wv16 = wq16 + 2 * 1048576;
    _Float16* wo16 = wq16 + 3 * 1048576;

    const int nround = (MROWS * EMB + 4 * EMB * EMB) / 1024;   // 20480
    round_all<<<nround, dim3(256), 0, stream>>>(x, Wq, Wk, Wv, Wo, xf, wq16, wk16, wv16, wo16);

    gemm_qkv<<<256, dim3(512), 0, stream>>>(xf, wq16, wk16, wv16, bq, bk, bv, qf, kf, vtf, 0);
    gemm_qkv<<<256, dim3(512), 0, stream>>>(xf, wq16, wk16, wv16, bq, bk, bv, qf, kf, vtf, 1);
    gemm_qkv<<<256, dim3(512), 0, stream>>>(xf, wq16, wk16, wv16, bq, bk, bv, qf, kf, vtf, 2);

    attn_mfma<<<dim3(L_SEQ / 128, B_SZ * NH), dim3(512), 0, stream>>>(qf, kf, vtf, cf);

    gemm_out<<<256, dim3(512), 0, stream>>>(cf, wo16, bo, out);
}

// Round 14
// 315.216 us; speedup vs baseline: 1.0603x; 1.0603x over previous
//
#include <hip/hip_runtime.h>
#include <math.h>

#define B_SZ  2
#define L_SEQ 8192
#define EMB   1024
#define NH    16
#define HDIM  64
#define WIN   128
#define MROWS (B_SZ*L_SEQ)

typedef __attribute__((ext_vector_type(8))) _Float16 f16x8;
typedef __attribute__((ext_vector_type(4))) _Float16 f16x4;
typedef __attribute__((ext_vector_type(4))) float f32x4;

__device__ __forceinline__ void gload16(const void* g, void* l) {
    __builtin_amdgcn_global_load_lds(
        (const __attribute__((address_space(1))) unsigned int*)g,
        (__attribute__((address_space(3))) unsigned int*)l, 16, 0, 0);
}

// ---------------- fused fp32 -> fp16 rounds (x + 4 weights) ----------------
__global__ __launch_bounds__(256)
void round_all(const float* __restrict__ x,
               const float* __restrict__ wq, const float* __restrict__ wk,
               const float* __restrict__ wv, const float* __restrict__ wo,
               _Float16* __restrict__ xf, _Float16* __restrict__ q16,
               _Float16* __restrict__ k16, _Float16* __restrict__ v16,
               _Float16* __restrict__ o16)
{
    const size_t NX = (size_t)MROWS * EMB, NW = (size_t)EMB * EMB;
    size_t gid = ((size_t)blockIdx.x * 256 + threadIdx.x) * 4;
    const float* src; _Float16* dst; size_t off;
    if (gid < NX)               { src = x;  dst = xf;  off = gid; }
    else if (gid < NX + NW)     { src = wq; dst = q16; off = gid - NX; }
    else if (gid < NX + 2*NW)   { src = wk; dst = k16; off = gid - NX - 2*NW + NW; }
    else if (gid < NX + 3*NW)   { src = wv; dst = v16; off = gid - NX - 2*NW; }
    else                        { src = wo; dst = o16; off = gid - NX - 3*NW; }
    float4 v = *(const float4*)(src + off);
    f16x4 o;
    o[0] = (_Float16)v.x; o[1] = (_Float16)v.y;
    o[2] = (_Float16)v.z; o[3] = (_Float16)v.w;
    *(f16x4*)(dst + off) = o;
}

// ============================================================================
// 256x256 GEMM, BK=64, 8 waves (2Mx4N), 128 KiB double-buffered LDS.
// R4 tail-read schedule + B0-HOLD (best measured). FROZEN.
// ============================================================================

#define STAGE_HT(ptr_, tb_, op_, h_, kt_)                                      \
    {                                                                          \
        char* d_ = smem + (op_) * 65536 + ((kt_) & 1) * 32768 + (h_) * 16384 + ldst; \
        const _Float16* s_ = (ptr_) + ((size_t)((tb_) + (h_) * 128 + srow6)) * 1024 + (kt_) * 64 + gch; \
        gload16(s_, d_);                                                       \
        gload16(s_ + 64 * 1024, d_ + 8192);                                    \
    }

#define DSREAD_A(qr_)                                                          \
    _Pragma("unroll")                                                          \
    for (int i_ = 0; i_ < 4; ++i_) {                                           \
        const int ro_ = (qr_) * 8192 + (i_ * 16 + frow) * 128;                 \
        af[i_][0] = *(const f16x8*)(Ab + ro_ + sb0);                           \
        af[i_][1] = *(const f16x8*)(Ab + ro_ + sb1);                           \
    }

#define DSREAD_B_TO(dst_, qc_)                                                 \
    _Pragma("unroll")                                                          \
    for (int j_ = 0; j_ < 2; ++j_) {                                           \
        const int ro_ = (brow + (qc_) * 32 + j_ * 16 + frow) * 128;            \
        dst_[j_][0] = *(const f16x8*)(Bb + ro_ + sb0);                         \
        dst_[j_][1] = *(const f16x8*)(Bb + ro_ + sb1);                         \
    }

#define MFMA16(qr_, qc_, barr_)                                                \
    __builtin_amdgcn_s_setprio(1);                                             \
    _Pragma("unroll")                                                          \
    for (int ks_ = 0; ks_ < 2; ++ks_)                                          \
        _Pragma("unroll")                                                      \
        for (int i_ = 0; i_ < 4; ++i_)                                         \
            _Pragma("unroll")                                                  \
            for (int j_ = 0; j_ < 2; ++j_)                                     \
                acc[(qr_) * 4 + i_][(qc_) * 2 + j_] =                          \
                    __builtin_amdgcn_mfma_f32_16x16x32_f16(                    \
                        af[i_][ks_], barr_[j_][ks_],                           \
                        acc[(qr_) * 4 + i_][(qc_) * 2 + j_], 0, 0, 0);         \
    __builtin_amdgcn_s_setprio(0);

#define BARM()                                                                 \
    asm volatile("" ::: "memory");                                             \
    __builtin_amdgcn_s_barrier();                                              \
    asm volatile("" ::: "memory");

#define GEMM8_CORE(Aptr, Bptr)                                                 \
    const int t = threadIdx.x;                                                 \
    const int wave = t >> 6, lane = t & 63;                                    \
    const int wr = wave >> 2, wc = wave & 3;                                   \
    const int frow = lane & 15, quad = lane >> 4;                              \
    const int srow6 = t >> 3;                                                  \
    const int gch = ((t & 7) ^ (srow6 & 7)) * 8;                               \
    const int ldst = t * 16;                                                   \
    const int sb0 = (quad ^ (frow & 7)) * 16, sb1 = sb0 ^ 64;                  \
    const int brow = (wc & 1) * 64;                                            \
    f32x4 acc[8][4] = {};                                                      \
    f16x8 af[4][2], bfA[2][2], bfB[2][2];                                      \
    STAGE_HT(Aptr, bm, 0, 0, 0) STAGE_HT(Aptr, bm, 0, 1, 0)                    \
    STAGE_HT(Bptr, bn, 1, 0, 0) STAGE_HT(Bptr, bn, 1, 1, 0)                    \
    for (int kt = 0; kt < 16; ++kt) {                                          \
        const char* Ab = smem + (kt & 1) * 32768 + wr * 16384;                 \
        const char* Bb = smem + 65536 + (kt & 1) * 32768 + (wc >> 1) * 16384;  \
        if (kt < 15) {                                                         \
            STAGE_HT(Aptr, bm, 0, 0, kt + 1)                                   \
            asm volatile("s_waitcnt vmcnt(2)" ::: "memory");                   \
        } else {                                                               \
            asm volatile("s_waitcnt vmcnt(0)" ::: "memory");                   \
        }                                                                      \
        BARM()                                                                 \
        DSREAD_A(0) DSREAD_B_TO(bfA, 0)  /* boundary reads (exposed) */        \
        MFMA16(0, 0, bfA)                                                      \
        DSREAD_B_TO(bfB, 1)              /* tail-read for next section */      \
        if (kt < 15) STAGE_HT(Aptr, bm, 0, 1, kt + 1)                          \
        BARM()                                                                 \
        MFMA16(0, 1, bfB)                                                      \
        DSREAD_A(1)                                                            \
        if (kt < 15) STAGE_HT(Bptr, bn, 1, 0, kt + 1)                          \
        BARM()                                                                 \
        MFMA16(1, 1, bfB)                                                      \
        if (kt < 15) STAGE_HT(Bptr, bn, 1, 1, kt + 1)                          \
        BARM()                                                                 \
        MFMA16(1, 0, bfA)                /* reuses held B0 — no re-read */     \
        BARM()                                                                 \
    }

// ---------------- fused QKV GEMM (768 blocks, fused wsel) ----------------
__global__ __launch_bounds__(512, 2)
void gemm_qkv(const _Float16* __restrict__ X,
              const _Float16* __restrict__ Wq, const _Float16* __restrict__ Wk,
              const _Float16* __restrict__ Wv,
              const float* __restrict__ bq, const float* __restrict__ bk,
              const float* __restrict__ bv,
              _Float16* __restrict__ qf, _Float16* __restrict__ kf,
              _Float16* __restrict__ vtf)
{
    __shared__ __attribute__((aligned(16))) char smem[131072];

    const int id = blockIdx.x;
    const int row = (id / 96) * 8 + (id & 7);   // 12 col-blocks of a row -> 1 XCD
    const int colq = (id >> 3) % 12;
    const int wsel = colq >> 2;                 // 0=q 1=k 2=v
    const int bm = row * 256, bn = (colq & 3) * 256;
    const _Float16* Bw = wsel == 0 ? Wq : wsel == 1 ? Wk : Wv;
    const float* bias = wsel == 0 ? bq : wsel == 1 ? bk : bv;
    // q pre-scale folds 1/sqrt(64) AND log2(e) so attn can use exp2 directly
    const float scale = wsel == 0 ? 0.18033688011112042f : 1.0f;

    GEMM8_CORE(X, Bw)

    // ---- epilogue: per-wave 8KB LDS slice (no cross-wave sync needed) ----
    char* Cw = smem + wave * 8192;              // 64 rows x 128B, XOR-swizzled
    const int bb = bm >> 13;
    const int l0 = (bm & (L_SEQ - 1)) + wr * 128;
    const int h = (bn >> 6) + wc;
    if (wsel < 2) {
        _Float16* dst = wsel == 0 ? qf : kf;
        const size_t hb = ((size_t)(bb * NH + h)) * L_SEQ * HDIM;
        #pragma unroll
        for (int ih = 0; ih < 2; ++ih) {
            asm volatile("" ::: "memory");
            #pragma unroll
            for (int i = 0; i < 4; ++i)
                #pragma unroll
                for (int j = 0; j < 4; ++j) {
                    const int lc = j * 16 + frow;
                    const float bvv = bias[bn + wc * 64 + lc];
                    #pragma unroll
                    for (int r = 0; r < 4; ++r) {
                        const int lr = i * 16 + quad * 4 + r;
                        const int bo = lr * 128 + ((lc * 2) ^ ((lr & 7) << 4));
                        *(_Float16*)(Cw + bo) = (_Float16)((acc[ih * 4 + i][j][r] + bvv) * scale);
                    }
                }
            asm volatile("" ::: "memory");
            #pragma unroll
            for (int p = 0; p < 8; ++p) {
                const int idx = p * 64 + lane;
                const int lr = idx >> 3, seg = idx & 7;
                const int bo = lr * 128 + ((seg * 16) ^ ((lr & 7) << 4));
                uint4 v = *(const uint4*)(Cw + bo);
                *(uint4*)&dst[hb + (size_t)(l0 + ih * 64 + lr) * HDIM + seg * 8] = v;
            }
        }
    } else {
        // V: stage transposed (col-major) so stores are contiguous along L
        const size_t hb = ((size_t)(bb * NH + h)) * HDIM * L_SEQ;
        #pragma unroll
        for (int ih = 0; ih < 2; ++ih) {
            asm volatile("" ::: "memory");
            #pragma unroll
            for (int i = 0; i < 4; ++i)
                #pragma unroll
                for (int j = 0; j < 4; ++j) {
                    const int lc = j * 16 + frow;
                    const float bvv = bias[bn + wc * 64 + lc];
                    #pragma unroll
                    for (int r = 0; r < 4; ++r) {
                        const int lr = i * 16 + quad * 4 + r;
                        const int bo = lc * 128 + ((lr * 2) ^ ((lc & 7) << 4));
                        *(_Float16*)(Cw + bo) = (_Float16)(acc[ih * 4 + i][j][r] + bvv);
                    }
                }
            asm volatile("" ::: "memory");
            #pragma unroll
            for (int p = 0; p < 8; ++p) {
                const int idx = p * 64 + lane;
                const int dc = idx >> 3, sl = idx & 7;
                const int bo = dc * 128 + ((sl * 16) ^ ((dc & 7) << 4));
                uint4 v = *(const uint4*)(Cw + bo);
                *(uint4*)&vtf[hb + (size_t)dc * L_SEQ + (l0 + ih * 64 + sl * 8)] = v;
            }
        }
    }
}

// ---------------- output GEMM ----------------
__global__ __launch_bounds__(512, 2)
void gemm_out(const _Float16* __restrict__ A, const _Float16* __restrict__ Bwm,
              const float* __restrict__ bias, float* __restrict__ C)
{
    constexpr int N = EMB;
    __shared__ __attribute__((aligned(16))) char smem[131072];

    const int id = blockIdx.x;
    const int row = (id / 32) * 8 + (id & 7);
    const int bm = row * 256, bn = ((id >> 3) & 3) * 256;

    GEMM8_CORE(A, Bwm)

    // ---- epilogue: direct f32 stores (64B contiguous per row-segment) ----
    #pragma unroll
    for (int i = 0; i < 8; ++i) {
        int m0 = bm + wr * 128 + i * 16 + quad * 4;
        #pragma unroll
        for (int j = 0; j < 4; ++j) {
            int n = bn + wc * 64 + j * 16 + frow;
            float bvv = bias[n];
            #pragma unroll
            for (int r = 0; r < 4; ++r)
                C[(size_t)(m0 + r) * N + n] = acc[i][j][r] + bvv;
        }
    }
}

// ---------------- banded flash attention, fp16 MFMA, 256-query tiles -------
// 16 waves (1024 thr) x 16 q-rows each: 4 waves/SIMD (was 2) for latency
// hiding; halo amortization cuts staging fetch 3072->2048 B per q-row.
// All 8 K/V tiles staged upfront (128 KiB LDS, one barrier), then a
// barrier-free per-wave section loop. Swapped QK^T -> in-register P^T ->
// mfma_16x16x16 PV. exp2-softmax (log2e folded into q pre-scale,
// v_exp_f32 via __builtin_amdgcn_exp2f). XCD-contiguity swizzle.
__global__ __launch_bounds__(1024)
void attn_mfma(const _Float16* __restrict__ qf, const _Float16* __restrict__ kf,
               const _Float16* __restrict__ vtf, _Float16* __restrict__ cf)
{
    __shared__ _Float16 Kt[8][4096];    // 64 KB
    __shared__ _Float16 Vt[8][4096];    // 64 KB

    const int t = threadIdx.x;
    const int wave = t >> 6, lane = t & 63;
    const int col = lane & 15, quad = lane >> 4;
    const int bh = blockIdx.y;
    const int xi = blockIdx.x;                      // 0..31
    const int xq = (xi & 7) * 4 + (xi >> 3);        // XCD-contiguous q-span
    const int q0 = xq * 256;
    const int oo = wave * 16;                       // wave's 16-row band

    // ---- stage ALL valid K/V tiles (half the threads each) ----
    const int tk = t & 511;
    const int srow = tk >> 3, sc = tk & 7;
    const int gq = sc ^ (srow & 7);
    #pragma unroll
    for (int kt = 0; kt < 8; kt++) {
        const int p0s = q0 - WIN + kt * 64;
        if (p0s < 0 || p0s > L_SEQ - 64) continue;  // block-uniform
        if (t < 512) {
            size_t kgi = ((size_t)bh * L_SEQ + p0s + srow) * HDIM + gq * 8;
            gload16(kf + kgi, (char*)&Kt[kt][0] + tk * 16);
        } else {
            size_t vgi = ((size_t)bh * HDIM + srow) * L_SEQ + p0s + gq * 8;
            gload16(vtf + vgi, (char*)&Vt[kt][0] + tk * 16);
        }
    }

    f16x8 qfr[2];
    {
        size_t qidx = ((size_t)bh * L_SEQ + q0 + oo + col) * HDIM + quad * 8;
        qfr[0] = *(const f16x8*)(qf + qidx);
        qfr[1] = *(const f16x8*)(qf + qidx + 32);
    }

    asm volatile("s_waitcnt vmcnt(0)" ::: "memory");
    __builtin_amdgcn_s_barrier();
    asm volatile("" ::: "memory");

    f32x4 o[4] = {};          // o[m][r] = O[q=col][d=m*16+quad*4+r]
    float lsum = 0.0f;

    // ---- barrier-free section loop (each wave: exactly 5 active) ----
    #pragma unroll
    for (int kt = 0; kt < 8; kt++) {
        const int p0 = q0 - WIN + kt * 64;
        if (p0 < 0 || p0 > L_SEQ - 64) continue;    // block-uniform
        const int relp = kt * 64 - WIN - oo;
        if (relp < -191 || relp > 143) continue;    // wave-uniform

        const char* Kb = (const char*)&Kt[kt][0];
        const char* Vb = (const char*)&Vt[kt][0];

        // ---- S^T = K Q^T ----
        f32x4 sT[4] = {};
        #pragma unroll
        for (int ks = 0; ks < 2; ks++)
            #pragma unroll
            for (int n = 0; n < 4; n++) {
                int off = (n * 16 + col) * 128 + (((ks * 4 + quad) ^ (col & 7)) * 16);
                f16x8 kfr = *(const f16x8*)(Kb + off);
                sT[n] = __builtin_amdgcn_mfma_f32_16x16x32_f16(kfr, qfr[ks], sT[n], 0, 0, 0);
            }
        // ---- band mask: only edge-clipped sections ----
        if (relp < -113 || relp > 65) {
            const int qrow = q0 + oo + col;
            #pragma unroll
            for (int n = 0; n < 4; n++)
                #pragma unroll
                for (int r = 0; r < 4; r++) {
                    int dlt = (p0 + n * 16 + quad * 4 + r) - qrow;
                    if (dlt < -WIN || dlt > WIN) sT[n][r] = -3e38f;
                }
        }
        // ---- exp2 (log2e pre-folded), per-lane sums, pack P^T ----
        f16x4 pT[4];
        #pragma unroll
        for (int n = 0; n < 4; n++)
            #pragma unroll
            for (int r = 0; r < 4; r++) {
                float pv = __builtin_amdgcn_exp2f(sT[n][r]);
                lsum += pv;
                pT[n][r] = (_Float16)pv;
            }
        // ---- O^T += V^T P^T via mfma_16x16x16 ----
        #pragma unroll
        for (int m = 0; m < 4; m++) {
            #pragma unroll
            for (int n = 0; n < 4; n++) {
                int off = (m * 16 + col) * 128 +
                          (((2 * n + (quad >> 1)) ^ (col & 7)) * 16) + (quad & 1) * 8;
                f16x4 vfr = *(const f16x4*)(Vb + off);
                o[m] = __builtin_amdgcn_mfma_f32_16x16x16f16(vfr, pT[n], o[m], 0, 0, 0);
            }
        }
    }

    // ---- deferred row-sum reduction over the 4 quad-lanes ----
    lsum += __shfl_xor(lsum, 16, 64);
    lsum += __shfl_xor(lsum, 32, 64);
    const float inv = 1.0f / lsum;

    // ---- normalize, store ctx fp16 (B,L,E): 4x 8B vector stores/lane ----
    const int b = bh >> 4, h = bh & 15;
    const size_t base = ((size_t)b * L_SEQ + q0 + oo + col) * EMB + h * HDIM;
    #pragma unroll
    for (int m = 0; m < 4; m++) {
        f16x4 ov;
        #pragma unroll
        for (int r = 0; r < 4; r++) ov[r] = (_Float16)(o[m][r] * inv);
        *(f16x4*)&cf[base + m * 16 + quad * 4] = ov;
    }
}

extern "C" void kernel_launch(void* const* d_in, const int* in_sizes, int n_in,
                              void* d_out, int out_size, void* d_ws, size_t ws_size,
                              hipStream_t stream) {
    const float* x  = (const float*)d_in[0];
    const float* Wq = (const float*)d_in[1];
    const float* Wk = (const float*)d_in[2];
    const float* Wv = (const float*)d_in[3];
    const float* Wo = (const float*)d_in[4];
    const float* bq = (const float*)d_in[5];
    const float* bk = (const float*)d_in[6];
    const float* bv = (const float*)d_in[7];
    const float* bo = (const float*)d_in[8];
    float* out = (float*)d_out;

    const size_t per = (size_t)B_SZ * NH * L_SEQ * HDIM;   // 16.7M elements
    _Float16* w16 = (_Float16*)d_ws;
    _Float16* xf   = w16;
    _Float16* qf   = w16 + per;       // (B,H,L,64), pre-scaled (1/8)*log2e
    _Float16* kf   = w16 + 2 * per;
    _Float16* vtf  = w16 + 3 * per;   // (B,H,64,L)
    _Float16* cf   = w16 + 4 * per;   // ctx (B,L,E)
    _Float16* wq16 = w16 + 5 * per;
    _Float16* wk16 = wq16 + 1048576;
    _Float16* wv16 = wq16 + 2 * 1048576;
    _Float16* wo16 = wq16 + 3 * 1048576;

    const int nround = (MROWS * EMB + 4 * EMB * EMB) / 1024;   // 20480
    round_all<<<nround, dim3(256), 0, stream>>>(x, Wq, Wk, Wv, Wo, xf, wq16, wk16, wv16, wo16);

    gemm_qkv<<<768, dim3(512), 0, stream>>>(xf, wq16, wk16, wv16, bq, bk, bv, qf, kf, vtf);

    attn_mfma<<<dim3(L_SEQ / 256, B_SZ * NH), dim3(1024), 0, stream>>>(qf, kf, vtf, cf);

    gemm_out<<<256, dim3(512), 0, stream>>>(cf, wo16, bo, out);
}

// Round 15
// 314.005 us; speedup vs baseline: 1.0643x; 1.0039x over previous
//
#include <hip/hip_runtime.h>
#include <math.h>

#define B_SZ  2
#define L_SEQ 8192
#define EMB   1024
#define NH    16
#define HDIM  64
#define WIN   128
#define MROWS (B_SZ*L_SEQ)

typedef __attribute__((ext_vector_type(8))) _Float16 f16x8;
typedef __attribute__((ext_vector_type(4))) _Float16 f16x4;
typedef __attribute__((ext_vector_type(4))) float f32x4;

__device__ __forceinline__ void gload16(const void* g, void* l) {
    __builtin_amdgcn_global_load_lds(
        (const __attribute__((address_space(1))) unsigned int*)g,
        (__attribute__((address_space(3))) unsigned int*)l, 16, 0, 0);
}

// ---------------- fused fp32 -> fp16 rounds (x + 4 weights) ----------------
__global__ __launch_bounds__(256)
void round_all(const float* __restrict__ x,
               const float* __restrict__ wq, const float* __restrict__ wk,
               const float* __restrict__ wv, const float* __restrict__ wo,
               _Float16* __restrict__ xf, _Float16* __restrict__ q16,
               _Float16* __restrict__ k16, _Float16* __restrict__ v16,
               _Float16* __restrict__ o16)
{
    const size_t NX = (size_t)MROWS * EMB, NW = (size_t)EMB * EMB;
    size_t gid = ((size_t)blockIdx.x * 256 + threadIdx.x) * 4;
    const float* src; _Float16* dst; size_t off;
    if (gid < NX)               { src = x;  dst = xf;  off = gid; }
    else if (gid < NX + NW)     { src = wq; dst = q16; off = gid - NX; }
    else if (gid < NX + 2*NW)   { src = wk; dst = k16; off = gid - NX - 2*NW + NW; }
    else if (gid < NX + 3*NW)   { src = wv; dst = v16; off = gid - NX - 2*NW; }
    else                        { src = wo; dst = o16; off = gid - NX - 3*NW; }
    float4 v = *(const float4*)(src + off);
    f16x4 o;
    o[0] = (_Float16)v.x; o[1] = (_Float16)v.y;
    o[2] = (_Float16)v.z; o[3] = (_Float16)v.w;
    *(f16x4*)(dst + off) = o;
}

// ============================================================================
// 256x256 GEMM, BK=64, 8 waves (2Mx4N), 128 KiB double-buffered LDS.
// R4 tail-read schedule + B0-HOLD (best measured). FROZEN.
// ============================================================================

#define STAGE_HT(ptr_, tb_, op_, h_, kt_)                                      \
    {                                                                          \
        char* d_ = smem + (op_) * 65536 + ((kt_) & 1) * 32768 + (h_) * 16384 + ldst; \
        const _Float16* s_ = (ptr_) + ((size_t)((tb_) + (h_) * 128 + srow6)) * 1024 + (kt_) * 64 + gch; \
        gload16(s_, d_);                                                       \
        gload16(s_ + 64 * 1024, d_ + 8192);                                    \
    }

#define DSREAD_A(qr_)                                                          \
    _Pragma("unroll")                                                          \
    for (int i_ = 0; i_ < 4; ++i_) {                                           \
        const int ro_ = (qr_) * 8192 + (i_ * 16 + frow) * 128;                 \
        af[i_][0] = *(const f16x8*)(Ab + ro_ + sb0);                           \
        af[i_][1] = *(const f16x8*)(Ab + ro_ + sb1);                           \
    }

#define DSREAD_B_TO(dst_, qc_)                                                 \
    _Pragma("unroll")                                                          \
    for (int j_ = 0; j_ < 2; ++j_) {                                           \
        const int ro_ = (brow + (qc_) * 32 + j_ * 16 + frow) * 128;            \
        dst_[j_][0] = *(const f16x8*)(Bb + ro_ + sb0);                         \
        dst_[j_][1] = *(const f16x8*)(Bb + ro_ + sb1);                         \
    }

#define MFMA16(qr_, qc_, barr_)                                                \
    __builtin_amdgcn_s_setprio(1);                                             \
    _Pragma("unroll")                                                          \
    for (int ks_ = 0; ks_ < 2; ++ks_)                                          \
        _Pragma("unroll")                                                      \
        for (int i_ = 0; i_ < 4; ++i_)                                         \
            _Pragma("unroll")                                                  \
            for (int j_ = 0; j_ < 2; ++j_)                                     \
                acc[(qr_) * 4 + i_][(qc_) * 2 + j_] =                          \
                    __builtin_amdgcn_mfma_f32_16x16x32_f16(                    \
                        af[i_][ks_], barr_[j_][ks_],                           \
                        acc[(qr_) * 4 + i_][(qc_) * 2 + j_], 0, 0, 0);         \
    __builtin_amdgcn_s_setprio(0);

#define BARM()                                                                 \
    asm volatile("" ::: "memory");                                             \
    __builtin_amdgcn_s_barrier();                                              \
    asm volatile("" ::: "memory");

#define GEMM8_CORE(Aptr, Bptr)                                                 \
    const int t = threadIdx.x;                                                 \
    const int wave = t >> 6, lane = t & 63;                                    \
    const int wr = wave >> 2, wc = wave & 3;                                   \
    const int frow = lane & 15, quad = lane >> 4;                              \
    const int srow6 = t >> 3;                                                  \
    const int gch = ((t & 7) ^ (srow6 & 7)) * 8;                               \
    const int ldst = t * 16;                                                   \
    const int sb0 = (quad ^ (frow & 7)) * 16, sb1 = sb0 ^ 64;                  \
    const int brow = (wc & 1) * 64;                                            \
    f32x4 acc[8][4] = {};                                                      \
    f16x8 af[4][2], bfA[2][2], bfB[2][2];                                      \
    STAGE_HT(Aptr, bm, 0, 0, 0) STAGE_HT(Aptr, bm, 0, 1, 0)                    \
    STAGE_HT(Bptr, bn, 1, 0, 0) STAGE_HT(Bptr, bn, 1, 1, 0)                    \
    for (int kt = 0; kt < 16; ++kt) {                                          \
        const char* Ab = smem + (kt & 1) * 32768 + wr * 16384;                 \
        const char* Bb = smem + 65536 + (kt & 1) * 32768 + (wc >> 1) * 16384;  \
        if (kt < 15) {                                                         \
            STAGE_HT(Aptr, bm, 0, 0, kt + 1)                                   \
            asm volatile("s_waitcnt vmcnt(2)" ::: "memory");                   \
        } else {                                                               \
            asm volatile("s_waitcnt vmcnt(0)" ::: "memory");                   \
        }                                                                      \
        BARM()                                                                 \
        DSREAD_A(0) DSREAD_B_TO(bfA, 0)  /* boundary reads (exposed) */        \
        MFMA16(0, 0, bfA)                                                      \
        DSREAD_B_TO(bfB, 1)              /* tail-read for next section */      \
        if (kt < 15) STAGE_HT(Aptr, bm, 0, 1, kt + 1)                          \
        BARM()                                                                 \
        MFMA16(0, 1, bfB)                                                      \
        DSREAD_A(1)                                                            \
        if (kt < 15) STAGE_HT(Bptr, bn, 1, 0, kt + 1)                          \
        BARM()                                                                 \
        MFMA16(1, 1, bfB)                                                      \
        if (kt < 15) STAGE_HT(Bptr, bn, 1, 1, kt + 1)                          \
        BARM()                                                                 \
        MFMA16(1, 0, bfA)                /* reuses held B0 — no re-read */     \
        BARM()                                                                 \
    }

// ---------------- fused QKV GEMM (768 blocks, fused wsel) ----------------
__global__ __launch_bounds__(512, 2)
void gemm_qkv(const _Float16* __restrict__ X,
              const _Float16* __restrict__ Wq, const _Float16* __restrict__ Wk,
              const _Float16* __restrict__ Wv,
              const float* __restrict__ bq, const float* __restrict__ bk,
              const float* __restrict__ bv,
              _Float16* __restrict__ qf, _Float16* __restrict__ kf,
              _Float16* __restrict__ vtf)
{
    __shared__ __attribute__((aligned(16))) char smem[131072];

    const int id = blockIdx.x;
    const int row = (id / 96) * 8 + (id & 7);   // 12 col-blocks of a row -> 1 XCD
    const int colq = (id >> 3) % 12;
    const int wsel = colq >> 2;                 // 0=q 1=k 2=v
    const int bm = row * 256, bn = (colq & 3) * 256;
    const _Float16* Bw = wsel == 0 ? Wq : wsel == 1 ? Wk : Wv;
    const float* bias = wsel == 0 ? bq : wsel == 1 ? bk : bv;
    // q pre-scale folds 1/sqrt(64) AND log2(e) so attn can use exp2 directly
    const float scale = wsel == 0 ? 0.18033688011112042f : 1.0f;

    GEMM8_CORE(X, Bw)

    // ---- epilogue: per-wave 8KB LDS slice (no cross-wave sync needed) ----
    char* Cw = smem + wave * 8192;              // 64 rows x 128B, XOR-swizzled
    const int bb = bm >> 13;
    const int l0 = (bm & (L_SEQ - 1)) + wr * 128;
    const int h = (bn >> 6) + wc;
    if (wsel < 2) {
        _Float16* dst = wsel == 0 ? qf : kf;
        const size_t hb = ((size_t)(bb * NH + h)) * L_SEQ * HDIM;
        #pragma unroll
        for (int ih = 0; ih < 2; ++ih) {
            asm volatile("" ::: "memory");
            #pragma unroll
            for (int i = 0; i < 4; ++i)
                #pragma unroll
                for (int j = 0; j < 4; ++j) {
                    const int lc = j * 16 + frow;
                    const float bvv = bias[bn + wc * 64 + lc];
                    #pragma unroll
                    for (int r = 0; r < 4; ++r) {
                        const int lr = i * 16 + quad * 4 + r;
                        const int bo = lr * 128 + ((lc * 2) ^ ((lr & 7) << 4));
                        *(_Float16*)(Cw + bo) = (_Float16)((acc[ih * 4 + i][j][r] + bvv) * scale);
                    }
                }
            asm volatile("" ::: "memory");
            #pragma unroll
            for (int p = 0; p < 8; ++p) {
                const int idx = p * 64 + lane;
                const int lr = idx >> 3, seg = idx & 7;
                const int bo = lr * 128 + ((seg * 16) ^ ((lr & 7) << 4));
                uint4 v = *(const uint4*)(Cw + bo);
                *(uint4*)&dst[hb + (size_t)(l0 + ih * 64 + lr) * HDIM + seg * 8] = v;
            }
        }
    } else {
        // V: stage transposed (col-major) so stores are contiguous along L
        const size_t hb = ((size_t)(bb * NH + h)) * HDIM * L_SEQ;
        #pragma unroll
        for (int ih = 0; ih < 2; ++ih) {
            asm volatile("" ::: "memory");
            #pragma unroll
            for (int i = 0; i < 4; ++i)
                #pragma unroll
                for (int j = 0; j < 4; ++j) {
                    const int lc = j * 16 + frow;
                    const float bvv = bias[bn + wc * 64 + lc];
                    #pragma unroll
                    for (int r = 0; r < 4; ++r) {
                        const int lr = i * 16 + quad * 4 + r;
                        const int bo = lc * 128 + ((lr * 2) ^ ((lc & 7) << 4));
                        *(_Float16*)(Cw + bo) = (_Float16)(acc[ih * 4 + i][j][r] + bvv);
                    }
                }
            asm volatile("" ::: "memory");
            #pragma unroll
            for (int p = 0; p < 8; ++p) {
                const int idx = p * 64 + lane;
                const int dc = idx >> 3, sl = idx & 7;
                const int bo = dc * 128 + ((sl * 16) ^ ((dc & 7) << 4));
                uint4 v = *(const uint4*)(Cw + bo);
                *(uint4*)&vtf[hb + (size_t)dc * L_SEQ + (l0 + ih * 64 + sl * 8)] = v;
            }
        }
    }
}

// ---------------- output GEMM ----------------
__global__ __launch_bounds__(512, 2)
void gemm_out(const _Float16* __restrict__ A, const _Float16* __restrict__ Bwm,
              const float* __restrict__ bias, float* __restrict__ C)
{
    constexpr int N = EMB;
    __shared__ __attribute__((aligned(16))) char smem[131072];

    const int id = blockIdx.x;
    const int row = (id / 32) * 8 + (id & 7);
    const int bm = row * 256, bn = ((id >> 3) & 3) * 256;

    GEMM8_CORE(A, Bwm)

    // ---- epilogue: direct f32 stores (64B contiguous per row-segment) ----
    #pragma unroll
    for (int i = 0; i < 8; ++i) {
        int m0 = bm + wr * 128 + i * 16 + quad * 4;
        #pragma unroll
        for (int j = 0; j < 4; ++j) {
            int n = bn + wc * 64 + j * 16 + frow;
            float bvv = bias[n];
            #pragma unroll
            for (int r = 0; r < 4; ++r)
                C[(size_t)(m0 + r) * N + n] = acc[i][j][r] + bvv;
        }
    }
}

// ---------------- banded flash attention, fp16 MFMA, 256-query tiles -------
// 16 waves (1024 thr) x 16 q-rows each, all 8 K/V tiles staged upfront,
// barrier-free section loop. Swapped QK^T -> in-register P^T ->
// mfma_16x16x16 PV. exp2-softmax (log2e pre-folded). ONES-TRICK row-sum:
// lsum computed by an extra MFMA column with constant all-ones A-operand
// (layout-proof: A is constant) — removes 16 VALU adds/section and the
// end shuffles, and normalizes by the same f16-rounded P that feeds PV.
// setprio(1) wraps MFMA clusters (T5; waves at different sections).
__global__ __launch_bounds__(1024)
void attn_mfma(const _Float16* __restrict__ qf, const _Float16* __restrict__ kf,
               const _Float16* __restrict__ vtf, _Float16* __restrict__ cf)
{
    __shared__ _Float16 Kt[8][4096];    // 64 KB
    __shared__ _Float16 Vt[8][4096];    // 64 KB

    const int t = threadIdx.x;
    const int wave = t >> 6, lane = t & 63;
    const int col = lane & 15, quad = lane >> 4;
    const int bh = blockIdx.y;
    const int xi = blockIdx.x;                      // 0..31
    const int xq = (xi & 7) * 4 + (xi >> 3);        // XCD-contiguous q-span
    const int q0 = xq * 256;
    const int oo = wave * 16;                       // wave's 16-row band

    // ---- stage ALL valid K/V tiles (half the threads each) ----
    const int tk = t & 511;
    const int srow = tk >> 3, sc = tk & 7;
    const int gq = sc ^ (srow & 7);
    #pragma unroll
    for (int kt = 0; kt < 8; kt++) {
        const int p0s = q0 - WIN + kt * 64;
        if (p0s < 0 || p0s > L_SEQ - 64) continue;  // block-uniform
        if (t < 512) {
            size_t kgi = ((size_t)bh * L_SEQ + p0s + srow) * HDIM + gq * 8;
            gload16(kf + kgi, (char*)&Kt[kt][0] + tk * 16);
        } else {
            size_t vgi = ((size_t)bh * HDIM + srow) * L_SEQ + p0s + gq * 8;
            gload16(vtf + vgi, (char*)&Vt[kt][0] + tk * 16);
        }
    }

    f16x8 qfr[2];
    {
        size_t qidx = ((size_t)bh * L_SEQ + q0 + oo + col) * HDIM + quad * 8;
        qfr[0] = *(const f16x8*)(qf + qidx);
        qfr[1] = *(const f16x8*)(qf + qidx + 32);
    }

    asm volatile("s_waitcnt vmcnt(0)" ::: "memory");
    __builtin_amdgcn_s_barrier();
    asm volatile("" ::: "memory");

    f32x4 o[4] = {};          // o[m][r] = O[q=col][d=m*16+quad*4+r]
    f32x4 o5 = {};            // ones-trick accumulator: o5[r] -> lsum[q=col]
    const f16x4 vones = {(_Float16)1.0f, (_Float16)1.0f,
                         (_Float16)1.0f, (_Float16)1.0f};

    // ---- barrier-free section loop (each wave: exactly 5 active) ----
    #pragma unroll
    for (int kt = 0; kt < 8; kt++) {
        const int p0 = q0 - WIN + kt * 64;
        if (p0 < 0 || p0 > L_SEQ - 64) continue;    // block-uniform
        const int relp = kt * 64 - WIN - oo;
        if (relp < -191 || relp > 143) continue;    // wave-uniform

        const char* Kb = (const char*)&Kt[kt][0];
        const char* Vb = (const char*)&Vt[kt][0];

        // ---- S^T = K Q^T ----
        f32x4 sT[4] = {};
        __builtin_amdgcn_s_setprio(1);
        #pragma unroll
        for (int ks = 0; ks < 2; ks++)
            #pragma unroll
            for (int n = 0; n < 4; n++) {
                int off = (n * 16 + col) * 128 + (((ks * 4 + quad) ^ (col & 7)) * 16);
                f16x8 kfr = *(const f16x8*)(Kb + off);
                sT[n] = __builtin_amdgcn_mfma_f32_16x16x32_f16(kfr, qfr[ks], sT[n], 0, 0, 0);
            }
        __builtin_amdgcn_s_setprio(0);
        // ---- band mask: only edge-clipped sections ----
        if (relp < -113 || relp > 65) {
            const int qrow = q0 + oo + col;
            #pragma unroll
            for (int n = 0; n < 4; n++)
                #pragma unroll
                for (int r = 0; r < 4; r++) {
                    int dlt = (p0 + n * 16 + quad * 4 + r) - qrow;
                    if (dlt < -WIN || dlt > WIN) sT[n][r] = -3e38f;
                }
        }
        // ---- exp2 (log2e pre-folded), pack P^T in regs ----
        f16x4 pT[4];
        #pragma unroll
        for (int n = 0; n < 4; n++)
            #pragma unroll
            for (int r = 0; r < 4; r++)
                pT[n][r] = (_Float16)__builtin_amdgcn_exp2f(sT[n][r]);
        // ---- O^T += V^T P^T; row-sum via ones-column MFMA ----
        __builtin_amdgcn_s_setprio(1);
        #pragma unroll
        for (int n = 0; n < 4; n++)
            o5 = __builtin_amdgcn_mfma_f32_16x16x16f16(vones, pT[n], o5, 0, 0, 0);
        #pragma unroll
        for (int m = 0; m < 4; m++) {
            #pragma unroll
            for (int n = 0; n < 4; n++) {
                int off = (m * 16 + col) * 128 +
                          (((2 * n + (quad >> 1)) ^ (col & 7)) * 16) + (quad & 1) * 8;
                f16x4 vfr = *(const f16x4*)(Vb + off);
                o[m] = __builtin_amdgcn_mfma_f32_16x16x16f16(vfr, pT[n], o[m], 0, 0, 0);
            }
        }
        __builtin_amdgcn_s_setprio(0);
    }

    // ---- normalize (lsum from ones-trick; all o5[r] equal) ----
    const float inv = 1.0f / o5[0];

    // ---- store ctx fp16 (B,L,E): 4x 8B vector stores/lane ----
    const int b = bh >> 4, h = bh & 15;
    const size_t base = ((size_t)b * L_SEQ + q0 + oo + col) * EMB + h * HDIM;
    #pragma unroll
    for (int m = 0; m < 4; m++) {
        f16x4 ov;
        #pragma unroll
        for (int r = 0; r < 4; r++) ov[r] = (_Float16)(o[m][r] * inv);
        *(f16x4*)&cf[base + m * 16 + quad * 4] = ov;
    }
}

extern "C" void kernel_launch(void* const* d_in, const int* in_sizes, int n_in,
                              void* d_out, int out_size, void* d_ws, size_t ws_size,
                              hipStream_t stream) {
    const float* x  = (const float*)d_in[0];
    const float* Wq = (const float*)d_in[1];
    const float* Wk = (const float*)d_in[2];
    const float* Wv = (const float*)d_in[3];
    const float* Wo = (const float*)d_in[4];
    const float* bq = (const float*)d_in[5];
    const float* bk = (const float*)d_in[6];
    const float* bv = (const float*)d_in[7];
    const float* bo = (const float*)d_in[8];
    float* out = (float*)d_out;

    const size_t per = (size_t)B_SZ * NH * L_SEQ * HDIM;   // 16.7M elements
    _Float16* w16 = (_Float16*)d_ws;
    _Float16* xf   = w16;
    _Float16* qf   = w16 + per;       // (B,H,L,64), pre-scaled (1/8)*log2e
    _Float16* kf   = w16 + 2 * per;
    _Float16* vtf  = w16 + 3 * per;   // (B,H,64,L)
    _Float16* cf   = w16 + 4 * per;   // ctx (B,L,E)
    _Float16* wq16 = w16 + 5 * per;
    _Float16* wk16 = wq16 + 1048576;
    _Float16* wv16 = wq16 + 2 * 1048576;
    _Float16* wo16 = wq16 + 3 * 1048576;

    const int nround = (MROWS * EMB + 4 * EMB * EMB) / 1024;   // 20480
    round_all<<<nround, dim3(256), 0, stream>>>(x, Wq, Wk, Wv, Wo, xf, wq16, wk16, wv16, wo16);

    gemm_qkv<<<768, dim3(512), 0, stream>>>(xf, wq16, wk16, wv16, bq, bk, bv, qf, kf, vtf);

    attn_mfma<<<dim3(L_SEQ / 256, B_SZ * NH), dim3(1024), 0, stream>>>(qf, kf, vtf, cf);

    gemm_out<<<256, dim3(512), 0, stream>>>(cf, wo16, bo, out);
}